// Round 9
// baseline (609.417 us; speedup 1.0000x reference)
//
#include <hip/hip_runtime.h>
#include <hip/hip_fp16.h>

#define D      256
#define NNODES 50000
#define KNBR   32
#define NGRP   8      // channel groups
#define GRPC   32     // channels per group

typedef _Float16 h8 __attribute__((ext_vector_type(8)));
typedef _Float16 h4 __attribute__((ext_vector_type(4)));
typedef _Float16 h2 __attribute__((ext_vector_type(2)));
typedef float    f4 __attribute__((ext_vector_type(4)));

// global->LDS direct: LDS base MUST be wave-uniform (HW: base + lane*16).
__device__ __forceinline__ void gll16(const void* g, void* l) {
  __builtin_amdgcn_global_load_lds(
      (const __attribute__((address_space(1))) void*)g,
      (__attribute__((address_space(3))) void*)l, 16, 0, 0);
}

// ws layout:
//   h_blk : _Float16 [NGRP][NNODES][GRPC]   25,600,000 B
//   Whi   : _Float16 [256*256]              at +25,600,000 (131,072 B)

// ---------------------------------------------------------------------------
// Kernel 0: W (fp32) -> fp16.
// ---------------------------------------------------------------------------
__global__ void wcvt(const float* __restrict__ W, _Float16* __restrict__ whi) {
  int i = (blockIdx.x * 256 + threadIdx.x) * 4;
  float4 w = *(const float4*)&W[i];
  union { _Float16 h[4]; uint2 u; } H;
  H.h[0] = (_Float16)w.x; H.h[1] = (_Float16)w.y;
  H.h[2] = (_Float16)w.z; H.h[3] = (_Float16)w.w;
  *(uint2*)&whi[i] = H.u;
}

// ---------------------------------------------------------------------------
// Kernel 1: h = x*Whi^T via 16x16x32 f16 MFMA, x split hi+lo (exact).
// Block = 128 rows x 128 cols, 4 waves; wave = 32 rows x 8 col-tiles.
// Double-buffered LDS W-slices; counted-vmcnt barrier keeps the 4 HBM
// x-prefetch loads in flight across the step boundary (T4).
// ---------------------------------------------------------------------------
__global__ __launch_bounds__(256, 2)
void gemm_mfma(const float* __restrict__ x, const _Float16* __restrict__ Whi,
               _Float16* __restrict__ hblk) {
  __shared__ _Float16 Ws[2][4][128][8];   // [buf][kq][colL][16B] = 2x8 KB

  const int tid  = threadIdx.x;
  const int lane = tid & 63;
  const int wv   = tid >> 6;
  const int wvu  = __builtin_amdgcn_readfirstlane(wv);
  const int c    = lane & 15;   // fragment row (A) / col (B)
  const int ko   = lane >> 4;   // k-chunk 0..3
  const int brow = blockIdx.x * 128;
  const int bcol = blockIdx.y * 128;

  const float* xrow[2];
#pragma unroll
  for (int tl = 0; tl < 2; tl++) {
    int ar = brow + wv * 32 + tl * 16 + c;
    if (ar >= NNODES) ar = NNODES - 1;
    xrow[tl] = &x[(size_t)ar * D];
  }

  f4 acc[2][8];
#pragma unroll
  for (int tl = 0; tl < 2; tl++)
#pragma unroll
    for (int j = 0; j < 8; j++) acc[tl][j] = (f4)(0.f);

  // Stage k-slice t of Whi (128 cols x 32 k = 512 x 16B units) into buf.
  auto stage = [&](int buf, int t) {
    const int k0 = t * 32;
#pragma unroll
    for (int q = 0; q < 2; q++) {
      const int fb   = wvu * 128 + q * 64;     // wave-uniform unit base
      const int f    = fb + lane;
      const int kq   = f >> 7;
      const int colL = f & 127;
      gll16(&Whi[(size_t)(bcol + colL) * D + k0 + kq * 8],
            (char*)Ws + ((size_t)buf * 512 + fb) * 16);
    }
  };

  float4 xv[8][2][2];   // fully-unrolled t-loop -> all indices static

  stage(0, 0);
#pragma unroll
  for (int tl = 0; tl < 2; tl++) {
    xv[0][tl][0] = *(const float4*)(xrow[tl] + ko * 8);
    xv[0][tl][1] = *(const float4*)(xrow[tl] + ko * 8 + 4);
  }
  __syncthreads();   // once: full drain is fine here

#pragma unroll
  for (int t = 0; t < 8; ++t) {
    const int buf = t & 1;
    if (t < 7) {
      stage(buf ^ 1, t + 1);                 // 2 gll16 (oldest vmcnt items)
      __builtin_amdgcn_sched_barrier(0);
#pragma unroll
      for (int tl = 0; tl < 2; tl++) {       // 4 HBM x loads (newer items)
        xv[t + 1][tl][0] = *(const float4*)(xrow[tl] + (t + 1) * 32 + ko * 8);
        xv[t + 1][tl][1] = *(const float4*)(xrow[tl] + (t + 1) * 32 + ko * 8 + 4);
      }
      __builtin_amdgcn_sched_barrier(0);
    }

    h8 ahi[2], alo[2];
#pragma unroll
    for (int tl = 0; tl < 2; tl++) {
      float xf[8] = {xv[t][tl][0].x, xv[t][tl][0].y, xv[t][tl][0].z, xv[t][tl][0].w,
                     xv[t][tl][1].x, xv[t][tl][1].y, xv[t][tl][1].z, xv[t][tl][1].w};
#pragma unroll
      for (int e = 0; e < 8; e++) {
        _Float16 hi = (_Float16)xf[e];
        ahi[tl][e] = hi;
        alo[tl][e] = (_Float16)(xf[e] - (float)hi);
      }
    }

#pragma unroll
    for (int j = 0; j < 8; j++) {
      h8 bhi = *(const h8*)&Ws[buf][ko][j * 16 + c][0];
#pragma unroll
      for (int tl = 0; tl < 2; tl++) {
        acc[tl][j] = __builtin_amdgcn_mfma_f32_16x16x32_f16(ahi[tl], bhi, acc[tl][j], 0, 0, 0);
        acc[tl][j] = __builtin_amdgcn_mfma_f32_16x16x32_f16(alo[tl], bhi, acc[tl][j], 0, 0, 0);
      }
    }

    if (t < 7) {
      // Drain only the 2 stage loads; leave the 4 x loads in flight.
      asm volatile("s_waitcnt vmcnt(4)" ::: "memory");
      __builtin_amdgcn_s_barrier();
      __builtin_amdgcn_sched_barrier(0);
    }
  }

  // C/D layout (HW-verified): col = lane&15 (=c), row = ko*4 + r.
#pragma unroll
  for (int tl = 0; tl < 2; tl++)
#pragma unroll
    for (int j = 0; j < 8; j++) {
      const int g  = (bcol >> 5) + (j >> 1);
      const int oc = (j & 1) * 16 + c;
#pragma unroll
      for (int r = 0; r < 4; r++) {
        const int n = brow + wv * 32 + tl * 16 + ko * 4 + r;
        if (n < NNODES)
          hblk[((size_t)g * NNODES + n) * GRPC + oc] = (_Float16)acc[tl][j][r];
      }
    }
}

// ---------------------------------------------------------------------------
// Kernel 2: trimmed-mean gather, group-blocked (per-XCD L2 resident).
// Block = (group g, 32 nodes) x 256 threads; thread = (node, 4 channels).
// Selection network (170 CE) via packed v_pk_min/max_f16.
// ---------------------------------------------------------------------------
__device__ __forceinline__ h2 h2min(h2 a, h2 b) {
  return __builtin_elementwise_min(a, b);
}
__device__ __forceinline__ h2 h2max(h2 a, h2 b) {
  return __builtin_elementwise_max(a, b);
}

template <int N, int P, int K>
__device__ __forceinline__ void oem_pass(h2* v) {
#pragma unroll
  for (int j = K % P; j + K < N; j += 2 * K) {
#pragma unroll
    for (int i = 0; i < K; i++) {
      if (i + j + K < N && ((i + j) / (2 * P) == (i + j + K) / (2 * P))) {
        h2 lo = h2min(v[i + j], v[i + j + K]);
        h2 hi = h2max(v[i + j], v[i + j + K]);
        v[i + j] = lo;
        v[i + j + K] = hi;
      }
    }
  }
}

__device__ __forceinline__ void sort16(h2* v) {
  oem_pass<16, 1, 1>(v);
  oem_pass<16, 2, 2>(v);  oem_pass<16, 2, 1>(v);
  oem_pass<16, 4, 4>(v);  oem_pass<16, 4, 2>(v);  oem_pass<16, 4, 1>(v);
  oem_pass<16, 8, 8>(v);  oem_pass<16, 8, 4>(v);  oem_pass<16, 8, 2>(v);
  oem_pass<16, 8, 1>(v);
}

__device__ __forceinline__ void ce(h2* v, int a, int b) {
  h2 lo = h2min(v[a], v[b]);
  h2 hi = h2max(v[a], v[b]);
  v[a] = lo; v[b] = hi;
}

// After this, v[14..17] hold ranks 14..17 of the 32 values (as a set).
__device__ __forceinline__ void select_mid4(h2* v) {
  sort16(v);
  sort16(v + 16);
#pragma unroll
  for (int i = 0; i < 16; i++) ce(v, i, 31 - i);   // L=v[0..15], H=v[16..31]
#pragma unroll
  for (int i = 0; i < 8; i++) ce(v, i, i + 8);      // top-8 of L -> v[8..15]
#pragma unroll
  for (int i = 8; i < 12; i++) ce(v, i, i + 4);     // top-4 -> v[12..15]
  ce(v, 12, 14); ce(v, 13, 15);                     // top-2 -> v[14..15]
#pragma unroll
  for (int i = 16; i < 24; i++) ce(v, i, i + 8);    // bot-8 of H -> v[16..23]
#pragma unroll
  for (int i = 16; i < 20; i++) ce(v, i, i + 4);    // bot-4 -> v[16..19]
  ce(v, 16, 18); ce(v, 17, 19);                     // bot-2 -> v[16..17]
}

__global__ __launch_bounds__(256, 8)
void trimmed_gather(const _Float16* __restrict__ hblk, const int* __restrict__ nbrs,
                    float* __restrict__ out) {
  __shared__ int nb[32 * 33];          // stride 33: bank = (nl+k)&31
  const int bid   = blockIdx.x;
  const int g     = bid & 7;           // group fastest -> XCD g affinity
  const int chunk = bid >> 3;
  const int n0    = chunk * 32;
  const int t     = threadIdx.x;

#pragma unroll
  for (int q = 0; q < 4; q++) {
    int e   = q * 256 + t;
    int idx = n0 * KNBR + e;
    if (idx >= NNODES * KNBR) idx = NNODES * KNBR - 1;   // tail clamp
    nb[(e >> 5) * 33 + (e & 31)] = nbrs[idx];
  }
  __syncthreads();

  const int nl = t >> 3;   // node local 0..31
  const int cp = t & 7;    // channel quad 0..7
  const _Float16* base = hblk + (size_t)g * NNODES * GRPC + cp * 4;

  h2 va[KNBR], vb[KNBR];
#pragma unroll
  for (int k = 0; k < KNBR; k++) {
    const int r = nb[nl * 33 + k];
    h4 w = *(const h4*)(base + (size_t)r * GRPC);
    va[k] = __builtin_shufflevector(w, w, 0, 1);
    vb[k] = __builtin_shufflevector(w, w, 2, 3);
  }

  select_mid4(va);
  select_mid4(vb);

  float4 res;
  res.x = ((float)va[14][0] + (float)va[15][0] + (float)va[16][0] + (float)va[17][0]) * 0.25f;
  res.y = ((float)va[14][1] + (float)va[15][1] + (float)va[16][1] + (float)va[17][1]) * 0.25f;
  res.z = ((float)vb[14][0] + (float)vb[15][0] + (float)vb[16][0] + (float)vb[17][0]) * 0.25f;
  res.w = ((float)vb[14][1] + (float)vb[15][1] + (float)vb[16][1] + (float)vb[17][1]) * 0.25f;

  const int n = n0 + nl;
  if (n < NNODES)
    *(float4*)&out[(size_t)n * D + g * GRPC + cp * 4] = res;
}

// ---------------------------------------------------------------------------
extern "C" void kernel_launch(void* const* d_in, const int* in_sizes, int n_in,
                              void* d_out, int out_size, void* d_ws, size_t ws_size,
                              hipStream_t stream) {
  const float* x    = (const float*)d_in[0];
  const int*   nbrs = (const int*)d_in[1];
  const float* W    = (const float*)d_in[2];
  float*       out  = (float*)d_out;

  _Float16* hblk = (_Float16*)d_ws;                       // 25.6 MB
  _Float16* Whi  = (_Float16*)((char*)d_ws + 25600000);   // 128 KB

  wcvt<<<dim3(64), dim3(256), 0, stream>>>(W, Whi);
  gemm_mfma<<<dim3((NNODES + 127) / 128, 2), dim3(256), 0, stream>>>(x, Whi, hblk);
  trimmed_gather<<<dim3(NGRP * ((NNODES + 31) / 32)), dim3(256), 0, stream>>>(
      hblk, nbrs, out);
}

// Round 11
// 214.134 us; speedup vs baseline: 2.8460x; 2.8460x over previous
//
#include <hip/hip_runtime.h>
#include <hip/hip_fp16.h>

#define D      256
#define NNODES 50000
#define KNBR   32
#define NGRP   8      // channel groups
#define GRPC   32     // channels per group

typedef _Float16 h8 __attribute__((ext_vector_type(8)));
typedef _Float16 h4 __attribute__((ext_vector_type(4)));
typedef _Float16 h2 __attribute__((ext_vector_type(2)));
typedef float    f4 __attribute__((ext_vector_type(4)));

// global->LDS direct: LDS base MUST be wave-uniform (HW: base + lane*16).
__device__ __forceinline__ void gll16(const void* g, void* l) {
  __builtin_amdgcn_global_load_lds(
      (const __attribute__((address_space(1))) void*)g,
      (__attribute__((address_space(3))) void*)l, 16, 0, 0);
}

// ws layout:
//   h_blk : _Float16 [NGRP][NNODES][GRPC]   25,600,000 B
//   Whi   : _Float16 [256*256]              at +25,600,000 (131,072 B)

// ---------------------------------------------------------------------------
// Kernel 0: W (fp32) -> fp16.
// ---------------------------------------------------------------------------
__global__ void wcvt(const float* __restrict__ W, _Float16* __restrict__ whi) {
  int i = (blockIdx.x * 256 + threadIdx.x) * 4;
  float4 w = *(const float4*)&W[i];
  union { _Float16 h[4]; uint2 u; } H;
  H.h[0] = (_Float16)w.x; H.h[1] = (_Float16)w.y;
  H.h[2] = (_Float16)w.z; H.h[3] = (_Float16)w.w;
  *(uint2*)&whi[i] = H.u;
}

// ---------------------------------------------------------------------------
// Kernel 1: h = x*Whi^T via 16x16x32 f16 MFMA, x split hi+lo (exact).
// WHOLE Whi (128 KB fp16) lives in LDS; each wave's full x row preloaded to
// registers. ONE barrier total; main loop = ds_read_b128 + MFMA only.
// Block = 512 thr = 8 waves x 16 rows; LDS layout [ks][ko][col][8 halves]
// (bank load perfectly even for the b128 col-tile reads).
// ---------------------------------------------------------------------------
__global__ __launch_bounds__(512, 2)
void gemm_mfma(const float* __restrict__ x, const _Float16* __restrict__ Whi,
               _Float16* __restrict__ hblk) {
  extern __shared__ _Float16 Ws[];   // 8192 x 16B units = 131072 B

  const int tid  = threadIdx.x;
  const int lane = tid & 63;
  const int wv   = tid >> 6;                            // wave 0..7
  const int wvu  = __builtin_amdgcn_readfirstlane(wv);
  const int c    = lane & 15;   // fragment row (A) / col (B)
  const int ko   = lane >> 4;   // k-chunk 0..3
  const int brow = blockIdx.x * 128;

  int ar = brow + wv * 16 + c;
  if (ar >= NNODES) ar = NNODES - 1;                    // clamp; stores guarded
  const float* xrow = &x[(size_t)ar * D];

  // ---- preload full x row (this lane's 8-float chunk per ks) ----
  float4 xr[8][2];
#pragma unroll
  for (int ks = 0; ks < 8; ks++) {
    xr[ks][0] = *(const float4*)(xrow + ks * 32 + ko * 8);
    xr[ks][1] = *(const float4*)(xrow + ks * 32 + ko * 8 + 4);
  }

  // ---- stage ALL of Whi into LDS: unit u = (ks*4+ko)*256 + col ----
  // wave wvu covers u in [wvu*1024, wvu*1024+1024), 16 chunks of 64.
#pragma unroll
  for (int q = 0; q < 16; q++) {
    const int fb  = wvu * 1024 + q * 64;        // wave-uniform unit base
    const int col = (q & 3) * 64 + lane;        // u & 255
    const int kk8 = wvu * 4 + (q >> 2);         // u >> 8  (= ks*4+ko)
    gll16(&Whi[(size_t)col * D + kk8 * 8], (char*)Ws + (size_t)fb * 16);
  }

  // ---- convert x row to hi/lo fp16 fragments (overlaps W staging) ----
  h8 ahi[8], alo[8];
#pragma unroll
  for (int ks = 0; ks < 8; ks++) {
    float xf[8] = {xr[ks][0].x, xr[ks][0].y, xr[ks][0].z, xr[ks][0].w,
                   xr[ks][1].x, xr[ks][1].y, xr[ks][1].z, xr[ks][1].w};
#pragma unroll
    for (int e = 0; e < 8; e++) {
      _Float16 hi = (_Float16)xf[e];
      ahi[ks][e] = hi;
      alo[ks][e] = (_Float16)(xf[e] - (float)hi);
    }
  }

  __syncthreads();   // the ONE barrier: W staged (drains vmcnt), all waves in

  f4 acc[16];
#pragma unroll
  for (int j = 0; j < 16; j++) acc[j] = (f4)(0.f);

  // ---- main loop: pure LDS + MFMA, no barriers, no global loads ----
#pragma unroll
  for (int ks = 0; ks < 8; ks++) {
#pragma unroll
    for (int j = 0; j < 16; j++) {
      const int u = (ks * 4 + ko) * 256 + j * 16 + c;
      h8 b = *(const h8*)(Ws + (size_t)u * 8);
      acc[j] = __builtin_amdgcn_mfma_f32_16x16x32_f16(ahi[ks], b, acc[j], 0, 0, 0);
      acc[j] = __builtin_amdgcn_mfma_f32_16x16x32_f16(alo[ks], b, acc[j], 0, 0, 0);
    }
  }

  // C/D layout (HW-verified): col = lane&15 (=c), row = ko*4 + r.
#pragma unroll
  for (int j = 0; j < 16; j++) {
    const int g  = j >> 1;
    const int oc = (j & 1) * 16 + c;
#pragma unroll
    for (int r = 0; r < 4; r++) {
      const int n = brow + wv * 16 + ko * 4 + r;
      if (n < NNODES)
        hblk[((size_t)g * NNODES + n) * GRPC + oc] = (_Float16)acc[j][r];
    }
  }
}

// ---------------------------------------------------------------------------
// Kernel 2: trimmed-mean gather, group-blocked (per-XCD L2 resident).
// Block = (group g, 32 nodes) x 256 threads; thread = (node, 4 channels).
// Selection network (170 CE) via packed v_pk_min/max_f16.
// ---------------------------------------------------------------------------
__device__ __forceinline__ h2 h2min(h2 a, h2 b) {
  return __builtin_elementwise_min(a, b);
}
__device__ __forceinline__ h2 h2max(h2 a, h2 b) {
  return __builtin_elementwise_max(a, b);
}

template <int N, int P, int K>
__device__ __forceinline__ void oem_pass(h2* v) {
#pragma unroll
  for (int j = K % P; j + K < N; j += 2 * K) {
#pragma unroll
    for (int i = 0; i < K; i++) {
      if (i + j + K < N && ((i + j) / (2 * P) == (i + j + K) / (2 * P))) {
        h2 lo = h2min(v[i + j], v[i + j + K]);
        h2 hi = h2max(v[i + j], v[i + j + K]);
        v[i + j] = lo;
        v[i + j + K] = hi;
      }
    }
  }
}

__device__ __forceinline__ void sort16(h2* v) {
  oem_pass<16, 1, 1>(v);
  oem_pass<16, 2, 2>(v);  oem_pass<16, 2, 1>(v);
  oem_pass<16, 4, 4>(v);  oem_pass<16, 4, 2>(v);  oem_pass<16, 4, 1>(v);
  oem_pass<16, 8, 8>(v);  oem_pass<16, 8, 4>(v);  oem_pass<16, 8, 2>(v);
  oem_pass<16, 8, 1>(v);
}

__device__ __forceinline__ void ce(h2* v, int a, int b) {
  h2 lo = h2min(v[a], v[b]);
  h2 hi = h2max(v[a], v[b]);
  v[a] = lo; v[b] = hi;
}

// After this, v[14..17] hold ranks 14..17 of the 32 values (as a set).
__device__ __forceinline__ void select_mid4(h2* v) {
  sort16(v);
  sort16(v + 16);
#pragma unroll
  for (int i = 0; i < 16; i++) ce(v, i, 31 - i);   // L=v[0..15], H=v[16..31]
#pragma unroll
  for (int i = 0; i < 8; i++) ce(v, i, i + 8);      // top-8 of L -> v[8..15]
#pragma unroll
  for (int i = 8; i < 12; i++) ce(v, i, i + 4);     // top-4 -> v[12..15]
  ce(v, 12, 14); ce(v, 13, 15);                     // top-2 -> v[14..15]
#pragma unroll
  for (int i = 16; i < 24; i++) ce(v, i, i + 8);    // bot-8 of H -> v[16..23]
#pragma unroll
  for (int i = 16; i < 20; i++) ce(v, i, i + 4);    // bot-4 -> v[16..19]
  ce(v, 16, 18); ce(v, 17, 19);                     // bot-2 -> v[16..17]
}

__global__ __launch_bounds__(256, 4)
void trimmed_gather(const _Float16* __restrict__ hblk, const int* __restrict__ nbrs,
                    float* __restrict__ out) {
  __shared__ int nb[32 * 33];          // stride 33: bank = (nl+k)&31
  const int bid   = blockIdx.x;
  const int g     = bid & 7;           // group fastest -> XCD g affinity
  const int chunk = bid >> 3;
  const int n0    = chunk * 32;
  const int t     = threadIdx.x;

#pragma unroll
  for (int q = 0; q < 4; q++) {
    int e   = q * 256 + t;
    int idx = n0 * KNBR + e;
    if (idx >= NNODES * KNBR) idx = NNODES * KNBR - 1;   // tail clamp
    nb[(e >> 5) * 33 + (e & 31)] = nbrs[idx];
  }
  __syncthreads();

  const int nl = t >> 3;   // node local 0..31
  const int cp = t & 7;    // channel quad 0..7
  const _Float16* base = hblk + (size_t)g * NNODES * GRPC + cp * 4;

  h2 va[KNBR], vb[KNBR];
#pragma unroll
  for (int k = 0; k < KNBR; k++) {
    const int r = nb[nl * 33 + k];
    h4 w = *(const h4*)(base + (size_t)r * GRPC);
    va[k] = __builtin_shufflevector(w, w, 0, 1);
    vb[k] = __builtin_shufflevector(w, w, 2, 3);
  }

  select_mid4(va);
  select_mid4(vb);

  float4 res;
  res.x = ((float)va[14][0] + (float)va[15][0] + (float)va[16][0] + (float)va[17][0]) * 0.25f;
  res.y = ((float)va[14][1] + (float)va[15][1] + (float)va[16][1] + (float)va[17][1]) * 0.25f;
  res.z = ((float)vb[14][0] + (float)vb[15][0] + (float)vb[16][0] + (float)vb[17][0]) * 0.25f;
  res.w = ((float)vb[14][1] + (float)vb[15][1] + (float)vb[16][1] + (float)vb[17][1]) * 0.25f;

  const int n = n0 + nl;
  if (n < NNODES)
    *(float4*)&out[(size_t)n * D + g * GRPC + cp * 4] = res;
}

// ---------------------------------------------------------------------------
extern "C" void kernel_launch(void* const* d_in, const int* in_sizes, int n_in,
                              void* d_out, int out_size, void* d_ws, size_t ws_size,
                              hipStream_t stream) {
  const float* x    = (const float*)d_in[0];
  const int*   nbrs = (const int*)d_in[1];
  const float* W    = (const float*)d_in[2];
  float*       out  = (float*)d_out;

  _Float16* hblk = (_Float16*)d_ws;                       // 25.6 MB
  _Float16* Whi  = (_Float16*)((char*)d_ws + 25600000);   // 128 KB

  wcvt<<<dim3(64), dim3(256), 0, stream>>>(W, Whi);
  gemm_mfma<<<dim3((NNODES + 127) / 128), dim3(512), 131072, stream>>>(x, Whi, hblk);
  trimmed_gather<<<dim3(NGRP * ((NNODES + 31) / 32)), dim3(256), 0, stream>>>(
      hblk, nbrs, out);
}